// Round 1
// baseline (1084.763 us; speedup 1.0000x reference)
//
#include <hip/hip_runtime.h>

// ---------------- problem constants ----------------
#define BATCH   32768
#define NLINE   411
#define NTILES  14            // 5 quad + 7 Ibr + 2 stat n-tiles of 128
#define PAIRS   7             // nt processed in pairs of 2 (256 cols)
#define ROWS    64            // batch rows per block
#define NBLK    (BATCH / ROWS)   // 512 blocks

typedef __attribute__((ext_vector_type(8))) short  short8;
typedef __attribute__((ext_vector_type(4))) float  f32x4;

// ---------------- workspace layout (bytes) ----------------
#define WS_SCALAR   0
#define WS_KROWS    64                       // 32768 f32
#define WS_MAPL     131136                   // 600 f32
#define WS_MAPG     133536                   // 138 f32 (pad to 134144)
#define WS_ATMP     134144                   // 822*600 f32 = 1972800
#define WS_BMF      2106944                  // 14*10*1024*16 = 2293760 -> 4400704
#define WS_ZERO_BYTES 2106944                // scalar..Atmp

__device__ __forceinline__ unsigned short f2bf(float f) {
    unsigned int u = __float_as_uint(f);
    unsigned int r = (u + 0x7FFFu + ((u >> 16) & 1u)) >> 16;
    return (unsigned short)r;
}

#if defined(__has_builtin)
#  if __has_builtin(__builtin_amdgcn_cvt_pk_bf16_f32)
#    define HAVE_PK_BF16 1
#  endif
#endif

__device__ __forceinline__ unsigned int pk2bf(float a, float b) {
#ifdef HAVE_PK_BF16
    typedef __bf16 bf16x2 __attribute__((ext_vector_type(2)));
    bf16x2 r = __builtin_amdgcn_cvt_pk_bf16_f32(a, b);
    return __builtin_bit_cast(unsigned int, r);
#else
    return (unsigned int)f2bf(a) | ((unsigned int)f2bf(b) << 16);
#endif
}

// ---------------- prep: masked column sums for mism ----------------
__global__ void prep_colsums(const float* __restrict__ MapL, const float* __restrict__ Mapg,
                             float* __restrict__ mapL_s, float* __restrict__ mapg_s) {
    int w = threadIdx.x >> 6, lane = threadIdx.x & 63;
    int row = blockIdx.x * 4 + w;
    const float* src;
    float* dst;
    if (row < 600)      { src = MapL + (size_t)row * 600; dst = mapL_s + row; }
    else if (row < 738) { src = Mapg + (size_t)(row - 600) * 600; dst = mapg_s + (row - 600); }
    else return;
    float s = 0.f;
    for (int j = lane; j < 600; j += 64)
        if (j != 299 && j != 599) s += src[j];
    for (int m = 32; m >= 1; m >>= 1) s += __shfl_xor(s, m);
    if (lane == 0) *dst = s;
}

// ---------------- prep: A = Ybr @ IM  (822x600), split-K fp32 with atomics ----------------
__global__ __launch_bounds__(256) void prep_A(const float* __restrict__ Ybr,
                                              const float* __restrict__ IM,
                                              float* __restrict__ Atmp) {
    int bid = blockIdx.x;
    int ks = bid & 3;
    int t2 = bid >> 2;
    int bc = t2 % 10, br = t2 / 10;          // 13 x 10 tiles of 64x64
    int r0 = br * 64, c0 = bc * 64;
    int kb = ks * 206;
    int ke = (kb + 206 < 822) ? kb + 206 : 822;

    __shared__ float Yt[64][33];
    __shared__ float Xt[32][65];
    int t = threadIdx.x;
    int tx = t & 15, ty = t >> 4;
    float c[4][4] = {};

    for (int kk = kb; kk < ke; kk += 32) {
        __syncthreads();
        for (int e = t; e < 2048; e += 256) {
            int yr = e >> 5, yk = e & 31;
            int gr = r0 + yr, gk = kk + yk;
            Yt[yr][yk] = (gr < 822 && gk < ke) ? Ybr[(size_t)gr * 822 + gk] : 0.f;
        }
        for (int e = t; e < 2048; e += 256) {
            int xk = e >> 6, xc = e & 63;
            int gk = kk + xk, gc = c0 + xc;
            Xt[xk][xc] = (gk < ke && gc < 600) ? IM[(size_t)gk * 600 + gc] : 0.f;
        }
        __syncthreads();
        for (int k2 = 0; k2 < 32; ++k2) {
            float a[4], b[4];
#pragma unroll
            for (int ii = 0; ii < 4; ++ii) a[ii] = Yt[ty * 4 + ii][k2];
#pragma unroll
            for (int jj = 0; jj < 4; ++jj) b[jj] = Xt[k2][tx * 4 + jj];
#pragma unroll
            for (int ii = 0; ii < 4; ++ii)
#pragma unroll
                for (int jj = 0; jj < 4; ++jj) c[ii][jj] += a[ii] * b[jj];
        }
    }
#pragma unroll
    for (int ii = 0; ii < 4; ++ii)
#pragma unroll
        for (int jj = 0; jj < 4; ++jj) {
            int gr = r0 + ty * 4 + ii, gc = c0 + tx * 4 + jj;
            if (gr < 822 && gc < 600) atomicAdd(Atmp + (size_t)gr * 600 + gc, c[ii][jj]);
        }
}

// ---------------- prep: pack combined B into MFMA-fragment order per (nt,kc) ----------------
// slot S -> (rc,kb): ig=S>>7, ks=(S>>6)&1, ln=S&63, rc = ig*16+(ln&15), kb = ks*32+((ln>>4)<<3)
__global__ void prep_packF(const float* __restrict__ Y, const float* __restrict__ Yconj,
                           const float* __restrict__ Mapg, const float* __restrict__ Atmp,
                           unsigned short* __restrict__ BmF) {
    int ntkc = blockIdx.x >> 2;
    int nt = ntkc / 10, kc = ntkc % 10;
    int S = (blockIdx.x & 3) * 256 + threadIdx.x;
    int ig = S >> 7, ks = (S >> 6) & 1, ln = S & 63;
    int rc = ig * 16 + (ln & 15);
    int kb = ks * 32 + ((ln >> 4) << 3);
    int n = nt * 128 + rc;
    unsigned short out[8];
#pragma unroll
    for (int j = 0; j < 8; ++j) {
        int k = kc * 64 + kb + j;
        float v = 0.f;
        if (k < 600) {
            if (n < 600) {
                if (n != 299 && n != 599)
                    v = Y[(size_t)n * 600 + k] + Yconj[(size_t)n * 600 + k];
            } else if (n >= 640 && n < 1536) {
                int idx = n - 640;
                int l = idx >> 1, h = idx & 1;
                if (l < NLINE) v = Atmp[(size_t)(h * NLINE + l) * 600 + k];
            } else if (n >= 1536) {
                int g = n - 1536;
                if (g < 138) v = Mapg[(size_t)g * 600 + k];
            }
        }
        out[j] = f2bf(v);
    }
    *(short8*)(BmF + (size_t)(ntkc * 1024 + S) * 8) = *(short8*)out;
}

// ---------------- A staging: f32 source -> bf16 fragment order in LDS ----------------
// 5120 slots (10 kc * 512). slot r within kc: g=r>>6 (rowblk=g>>1, ks=g&1), ln=r&63
// row = rowblk*16 + (ln&15), k = kc*64 + ks*32 + (ln>>4)*8
__device__ __forceinline__ void stage_a(const float* __restrict__ src, int b0,
                                        short8* Abuf, int t) {
#pragma unroll
    for (int h = 0; h < 2; ++h) {
        f32x4 x[20];
        int Sb = h * 2560;
#pragma unroll
        for (int m = 0; m < 10; ++m) {
            int S = Sb + m * 256 + t;
            int kc = S >> 9, r = S & 511;
            int g = r >> 6, ln = r & 63;
            int row = b0 + ((g >> 1) << 4) + (ln & 15);
            int k = (kc << 6) + ((g & 1) << 5) + ((ln >> 4) << 3);
            if (k < 600) {          // k is a multiple of 8; 600%8==0 so chunks are all-in or all-out
                const f32x4* p = (const f32x4*)(src + (size_t)row * 600 + k);
                x[2 * m] = p[0]; x[2 * m + 1] = p[1];
            } else {
                f32x4 z = {0.f, 0.f, 0.f, 0.f};
                x[2 * m] = z; x[2 * m + 1] = z;
            }
        }
#pragma unroll
        for (int m = 0; m < 10; ++m) {
            int S = Sb + m * 256 + t;
            f32x4 a = x[2 * m], b = x[2 * m + 1];
            Abuf[S] = __builtin_bit_cast(short8,
                make_uint4(pk2bf(a[0], a[1]), pk2bf(a[2], a[3]),
                           pk2bf(b[0], b[1]), pk2bf(b[2], b[3])));
        }
    }
}

// ---------------- B prefetch: global_load_lds of one nt-pair tile (2*16KB) ----------------
__device__ __forceinline__ void issue_b(const unsigned short* __restrict__ BmF,
                                        int p, int kc, short8* dst, int t) {
#pragma unroll
    for (int m = 0; m < 8; ++m) {
        int S = m * 256 + t;                 // 0..2047
        int ntl2 = S >> 10, Sl = S & 1023;
        const unsigned short* src = BmF +
            (size_t)(((p * 2 + ntl2) * 10 + kc) * 1024 + Sl) * 8;
        __builtin_amdgcn_global_load_lds(
            (const __attribute__((address_space(1))) unsigned int*)src,
            (__attribute__((address_space(3))) unsigned int*)(dst + S), 16, 0, 0);
    }
}

// ---------------- main fused kernel: persistent A rowtile, nt sweep ----------------
__global__ __launch_bounds__(256, 1) void kkt_main(
    const float* __restrict__ Volt, const float* __restrict__ nolp,
    const float* __restrict__ PG, const float* __restrict__ PL,
    const float* __restrict__ mu_gu, const float* __restrict__ mu_gd,
    const float* __restrict__ mu_vu, const float* __restrict__ mu_vd,
    const float* __restrict__ mu_iu,
    const float* __restrict__ Gmax, const float* __restrict__ Gmin,
    const float* __restrict__ CPg,
    const unsigned short* __restrict__ BmF,
    const float* __restrict__ mapLs, const float* __restrict__ mapgs,
    float* __restrict__ kkt_rows, float* __restrict__ scalar_acc) {

    __shared__ short8 Abuf[5120];       // 80 KB: A rowtile, all K, fragment order
    __shared__ short8 Bsm[2][2048];     // 64 KB: double-buffered nt-pair B tile
    __shared__ float  mls[600];
    __shared__ float  sacc;

    int t = threadIdx.x, lane = t & 63, w = t >> 6;
    int b0 = blockIdx.x * ROWS;
    int ntl = w >> 1, wc2 = w & 1;      // wave w -> cols [w*64, w*64+64) of the 256-col pair

    if (t == 0) sacc = 0.f;
    for (int j = t; j < 600; j += 256) mls[j] = mapLs[j];

    stage_a(Volt, b0, Abuf, t);         // A for nt 0..11
    issue_b(BmF, 0, 0, &Bsm[0][0], t);
    __syncthreads();                    // drains lgkm (A writes) + vm (B0)

    f32x4 acc[4][4] = {};
    float dscal = 0.f;                  // |Volt[:,300]| duty, per wave (lane 0)

    for (int s = 0; s < PAIRS * 10; ++s) {
        int p = s / 10, kc = s % 10;

        if (s == 60) {                  // nt pair 6 (stat): A comes from nolp
            stage_a(nolp, b0, Abuf, t);
            __syncthreads();
        }
        int sn = s + 1;
        if (sn < PAIRS * 10) issue_b(BmF, sn / 10, sn % 10, &Bsm[sn & 1][0], t);

        // ---- MFMA on current buffers ----
        const short8* Ak = Abuf + kc * 512;
        const short8* Bp = &Bsm[s & 1][ntl * 1024];
#pragma unroll
        for (int ks = 0; ks < 2; ++ks) {
            short8 af[4], bfr[4];
#pragma unroll
            for (int ii = 0; ii < 4; ++ii) af[ii] = Ak[(((ii << 1) | ks) << 6) + lane];
#pragma unroll
            for (int jj = 0; jj < 4; ++jj)
                bfr[jj] = Bp[(((((wc2 << 2) | jj) << 1) | ks) << 6) + lane];
#pragma unroll
            for (int ii = 0; ii < 4; ++ii)
#pragma unroll
                for (int jj = 0; jj < 4; ++jj)
                    acc[ii][jj] = __builtin_amdgcn_mfma_f32_16x16x32_bf16(af[ii], bfr[jj], acc[ii][jj], 0, 0, 0);
        }

        // ---- row duties, spread over the first 16 steps (1 row per wave per step) ----
        if (s < 16) {
            int r = b0 + s * 4 + w;
            const float* vrow = Volt + (size_t)r * 600;
            float sd = 0.f;
            for (int j = lane; j < 300; j += 64) {
                float vr = vrow[j], vi = vrow[300 + j];
                float muu = mu_vu[(size_t)r * 300 + j];
                float mud = mu_vd[(size_t)r * 300 + j];
                float sq = vr * vr, si = vi * vi;
                float vu = sq + si - 1.1236f;
                float vd = 0.8836f - sq + si;
                sd += fmaxf(vu, 0.f) + fmaxf(vd, 0.f) + fabsf(muu * vu) + fabsf(mud * vd)
                    + fmaxf(-muu, 0.f) + fmaxf(-mud, 0.f);
            }
            float s2 = 0.f;
            for (int j = lane; j < 600; j += 64) s2 += PL[(size_t)r * 600 + j] * mls[j];
            sd += 32768.0f * s2;
            for (int m = 32; m >= 1; m >>= 1) sd += __shfl_xor(sd, m);
            if (lane == 0) {
                atomicAdd(kkt_rows + r, sd);
                dscal += fabsf(vrow[300]);
            }
        }

        // ---- epilogue at end of each nt pair ----
        // C/D layout (m89): col = lane&15, row = (lane>>4)*4 + reg
        if (kc == 9) {
            int cb = p * 4 + w;                 // col-block 0..27 (64 cols each)
            int c0 = cb * 64;
            if (cb < 10) {
                // quad: global scalar += sum u*v (v read fp32)
                float qa = 0.f;
#pragma unroll
                for (int ii = 0; ii < 4; ++ii)
#pragma unroll
                    for (int jj = 0; jj < 4; ++jj) {
                        int col = c0 + jj * 16 + (lane & 15);
                        if (col < 600) {
#pragma unroll
                            for (int r2 = 0; r2 < 4; ++r2) {
                                int row = ii * 16 + ((lane >> 4) << 2) + r2;
                                qa += acc[ii][jj][r2] * Volt[(size_t)(b0 + row) * 600 + col];
                            }
                        }
                    }
                for (int m = 32; m >= 1; m >>= 1) qa += __shfl_xor(qa, m);
                if (lane == 0) atomicAdd(&sacc, qa);
            } else if (cb < 24) {
                // Ibr: i_up = re^2 + im^2 - 1 on interleaved column pairs
                float racc[16];
#pragma unroll
                for (int q2 = 0; q2 < 16; ++q2) racc[q2] = 0.f;
#pragma unroll
                for (int ii = 0; ii < 4; ++ii)
#pragma unroll
                    for (int jj = 0; jj < 4; ++jj) {
                        int col = c0 + jj * 16 + (lane & 15);
                        int l = (col - 640) >> 1;
#pragma unroll
                        for (int r2 = 0; r2 < 4; ++r2) {
                            float u = acc[ii][jj][r2];
                            float up = __shfl_xor(u, 1);
                            float contrib = 0.f;
                            if (l < NLINE && !(lane & 1)) {
                                int row = ii * 16 + ((lane >> 4) << 2) + r2;
                                float iu = u * u + up * up - 1.0f;
                                float mu = mu_iu[(size_t)(b0 + row) * NLINE + l];
                                contrib = fmaxf(iu, 0.f) + fabsf(mu * iu) + fmaxf(-mu, 0.f);
                            }
                            racc[ii * 4 + r2] += contrib;
                        }
                    }
#pragma unroll
                for (int q2 = 0; q2 < 16; ++q2) {
                    float v = racc[q2];
                    v += __shfl_xor(v, 1); v += __shfl_xor(v, 2);
                    v += __shfl_xor(v, 4); v += __shfl_xor(v, 8);
                    if ((lane & 15) == 0) {
                        int row = (q2 >> 2) * 16 + ((lane >> 4) << 2) + (q2 & 3);
                        atomicAdd(kkt_rows + b0 + row, v);
                    }
                }
            } else {
                // stat + gen-limit + P_Gens part of mism
                float racc[16];
#pragma unroll
                for (int q2 = 0; q2 < 16; ++q2) racc[q2] = 0.f;
#pragma unroll
                for (int ii = 0; ii < 4; ++ii)
#pragma unroll
                    for (int jj = 0; jj < 4; ++jj) {
                        int col = c0 + jj * 16 + (lane & 15);
                        int g = col - 1536;
#pragma unroll
                        for (int r2 = 0; r2 < 4; ++r2) {
                            float contrib = 0.f;
                            if (g < 138) {
                                int row = ii * 16 + ((lane >> 4) << 2) + r2;
                                size_t ix = (size_t)(b0 + row) * 138 + g;
                                float u = acc[ii][jj][r2];
                                float gu = mu_gu[ix], gd = mu_gd[ix], pg = PG[ix];
                                float gmx = Gmax[g], gmn = Gmin[g];
                                float cst = (g < 69) ? CPg[g] : 0.f;
                                float t1 = pg - gmx, t2 = gmn - pg;
                                float st = u + gu - gd - cst;
                                contrib = fabsf(st) + fmaxf(t1, 0.f) + fmaxf(t2, 0.f)
                                        + (fabsf(gu * t1) + fabsf(gd * t2)) * (1.0f / 69.0f)
                                        + fmaxf(-gu, 0.f) + fmaxf(-gd, 0.f)
                                        - 32768.0f * pg * mapgs[g];
                            }
                            racc[ii * 4 + r2] += contrib;
                        }
                    }
#pragma unroll
                for (int q2 = 0; q2 < 16; ++q2) {
                    float v = racc[q2];
                    v += __shfl_xor(v, 1); v += __shfl_xor(v, 2);
                    v += __shfl_xor(v, 4); v += __shfl_xor(v, 8);
                    if ((lane & 15) == 0) {
                        int row = (q2 >> 2) * 16 + ((lane >> 4) << 2) + (q2 & 3);
                        atomicAdd(kkt_rows + b0 + row, v);
                    }
                }
            }
            // reset accumulator for next pair
#pragma unroll
            for (int ii = 0; ii < 4; ++ii)
#pragma unroll
                for (int jj = 0; jj < 4; ++jj) {
                    f32x4 z = {0.f, 0.f, 0.f, 0.f};
                    acc[ii][jj] = z;
                }
        }

        __syncthreads();   // drains vm (B(s+1) landed) + guards buffer reuse
    }

    if (lane == 0) atomicAdd(&sacc, dscal);
    __syncthreads();
    if (t == 0) atomicAdd(scalar_acc, sacc);
}

// ---------------- finalize ----------------
__global__ void finalize_k(const float* __restrict__ kkt_rows, const float* __restrict__ scalar_acc,
                           float* __restrict__ out) {
    int i = blockIdx.x * 256 + threadIdx.x;
    out[i] = kkt_rows[i] + scalar_acc[0];
}

extern "C" void kernel_launch(void* const* d_in, const int* in_sizes, int n_in,
                              void* d_out, int out_size, void* d_ws, size_t ws_size,
                              hipStream_t stream) {
    const float* Volt  = (const float*)d_in[0];
    const float* PG    = (const float*)d_in[1];
    const float* PL    = (const float*)d_in[2];
    const float* nolp  = (const float*)d_in[3];
    const float* mu_gu = (const float*)d_in[4];
    const float* mu_gd = (const float*)d_in[5];
    const float* mu_vu = (const float*)d_in[6];
    const float* mu_vd = (const float*)d_in[7];
    const float* mu_iu = (const float*)d_in[8];
    const float* Y     = (const float*)d_in[9];
    const float* Yconj = (const float*)d_in[10];
    const float* Ybr   = (const float*)d_in[11];
    const float* IM    = (const float*)d_in[12];
    const float* Mapg  = (const float*)d_in[13];
    const float* MapL  = (const float*)d_in[14];
    const float* Gmax  = (const float*)d_in[15];
    const float* Gmin  = (const float*)d_in[16];
    const float* CPg   = (const float*)d_in[17];

    char* ws = (char*)d_ws;
    float* scalar_acc       = (float*)(ws + WS_SCALAR);
    float* kkt_rows         = (float*)(ws + WS_KROWS);
    float* mapLs            = (float*)(ws + WS_MAPL);
    float* mapgs            = (float*)(ws + WS_MAPG);
    float* Atmp             = (float*)(ws + WS_ATMP);
    unsigned short* BmF     = (unsigned short*)(ws + WS_BMF);

    hipMemsetAsync(d_ws, 0, WS_ZERO_BYTES, stream);
    prep_colsums<<<185, 256, 0, stream>>>(MapL, Mapg, mapLs, mapgs);
    prep_A<<<520, 256, 0, stream>>>(Ybr, IM, Atmp);
    prep_packF<<<560, 256, 0, stream>>>(Y, Yconj, Mapg, Atmp, BmF);
    kkt_main<<<NBLK, 256, 0, stream>>>(Volt, nolp, PG, PL, mu_gu, mu_gd, mu_vu, mu_vd,
                                       mu_iu, Gmax, Gmin, CPg, BmF, mapLs, mapgs,
                                       kkt_rows, scalar_acc);
    finalize_k<<<BATCH / 256, 256, 0, stream>>>(kkt_rows, scalar_acc, (float*)d_out);
}

// Round 2
// 816.663 us; speedup vs baseline: 1.3283x; 1.3283x over previous
//
#include <hip/hip_runtime.h>

// ---------------- problem constants ----------------
#define BATCH   32768
#define NLINE   411
#define NTILES  14            // 5 quad + 7 Ibr + 2 stat n-tiles of 128
#define RTILES  256           // 32768 / 128

typedef __attribute__((ext_vector_type(8))) short  short8;
typedef __attribute__((ext_vector_type(4))) float  f32x4;

// ---------------- workspace layout (bytes) ----------------
#define WS_SCALAR   0
#define WS_KROWS    64                       // 32768 f32
#define WS_MAPL     131136                   // 600 f32
#define WS_MAPG     133536                   // 138 f32 (pad to 134144)
#define WS_ATMP     134144                   // 822*600 f32 = 1972800
#define WS_BMF      2106944                  // 14*10*1024*16 = 2293760
#define WS_VBF      4400704                  // 32768*640 bf16 = 41943040
#define WS_NEED_FAST (4400704 + 41943040)    // 46343744
#define WS_ZERO_BYTES 2106944                // scalar..Atmp

__device__ __forceinline__ unsigned short f2bf(float f) {
    unsigned int u = __float_as_uint(f);
    unsigned int r = (u + 0x7FFFu + ((u >> 16) & 1u)) >> 16;
    return (unsigned short)r;
}

#if defined(__has_builtin)
#  if __has_builtin(__builtin_amdgcn_cvt_pk_bf16_f32)
#    define HAVE_PK_BF16 1
#  endif
#endif

__device__ __forceinline__ unsigned int pk2bf(float a, float b) {
#ifdef HAVE_PK_BF16
    typedef __bf16 bf16x2 __attribute__((ext_vector_type(2)));
    bf16x2 r = __builtin_amdgcn_cvt_pk_bf16_f32(a, b);
    return __builtin_bit_cast(unsigned int, r);
#else
    return (unsigned int)f2bf(a) | ((unsigned int)f2bf(b) << 16);
#endif
}

// ---------------- prep: A = Ybr @ IM  (822x600), split-K fp32 with atomics ----------------
__global__ __launch_bounds__(256) void prep_A(const float* __restrict__ Ybr,
                                              const float* __restrict__ IM,
                                              float* __restrict__ Atmp) {
    int bid = blockIdx.x;
    int ks = bid & 3;
    int t2 = bid >> 2;
    int bc = t2 % 10, br = t2 / 10;          // 13 x 10 tiles of 64x64
    int r0 = br * 64, c0 = bc * 64;
    int kb = ks * 206;
    int ke = (kb + 206 < 822) ? kb + 206 : 822;

    __shared__ float Yt[64][33];
    __shared__ float Xt[32][65];
    int t = threadIdx.x;
    int tx = t & 15, ty = t >> 4;
    float c[4][4] = {};

    for (int kk = kb; kk < ke; kk += 32) {
        __syncthreads();
        for (int e = t; e < 2048; e += 256) {
            int yr = e >> 5, yk = e & 31;
            int gr = r0 + yr, gk = kk + yk;
            Yt[yr][yk] = (gr < 822 && gk < ke) ? Ybr[(size_t)gr * 822 + gk] : 0.f;
        }
        for (int e = t; e < 2048; e += 256) {
            int xk = e >> 6, xc = e & 63;
            int gk = kk + xk, gc = c0 + xc;
            Xt[xk][xc] = (gk < ke && gc < 600) ? IM[(size_t)gk * 600 + gc] : 0.f;
        }
        __syncthreads();
        for (int k2 = 0; k2 < 32; ++k2) {
            float a[4], b[4];
#pragma unroll
            for (int ii = 0; ii < 4; ++ii) a[ii] = Yt[ty * 4 + ii][k2];
#pragma unroll
            for (int jj = 0; jj < 4; ++jj) b[jj] = Xt[k2][tx * 4 + jj];
#pragma unroll
            for (int ii = 0; ii < 4; ++ii)
#pragma unroll
                for (int jj = 0; jj < 4; ++jj) c[ii][jj] += a[ii] * b[jj];
        }
    }
#pragma unroll
    for (int ii = 0; ii < 4; ++ii)
#pragma unroll
        for (int jj = 0; jj < 4; ++jj) {
            int gr = r0 + ty * 4 + ii, gc = c0 + tx * 4 + jj;
            if (gr < 822 && gc < 600) atomicAdd(Atmp + (size_t)gr * 600 + gc, c[ii][jj]);
        }
}

// ---------------- prep_misc: colsums (185) + packF (560) + Volt->Vbf conv (8192) ----------------
// slot S -> (rc,kb): ig=S>>7, ks=(S>>6)&1, ln=S&63, rc = ig*16+(ln&15), kb = ks*32+((ln>>4)<<3)
__global__ __launch_bounds__(256) void prep_misc(
    const float* __restrict__ MapL, const float* __restrict__ Mapg,
    float* __restrict__ mapL_s, float* __restrict__ mapg_s,
    const float* __restrict__ Y, const float* __restrict__ Yconj,
    const float* __restrict__ Atmp, unsigned short* __restrict__ BmF,
    const float* __restrict__ Volt, unsigned short* __restrict__ Vbf, int doConv) {
    int bid = blockIdx.x;
    int t = threadIdx.x;
    int w = t >> 6, lane = t & 63;

    if (bid < 185) {
        // masked column sums for mism
        int row = bid * 4 + w;
        const float* src;
        float* dst;
        if (row < 600)      { src = MapL + (size_t)row * 600; dst = mapL_s + row; }
        else if (row < 738) { src = Mapg + (size_t)(row - 600) * 600; dst = mapg_s + (row - 600); }
        else return;
        float s = 0.f;
        for (int j = lane; j < 600; j += 64)
            if (j != 299 && j != 599) s += src[j];
        for (int m = 32; m >= 1; m >>= 1) s += __shfl_xor(s, m);
        if (lane == 0) *dst = s;
    } else if (bid < 745) {
        // pack combined B into MFMA-fragment order per (nt,kc)
        int b2 = bid - 185;
        int ntkc = b2 >> 2;
        int nt = ntkc / 10, kc = ntkc % 10;
        int S = (b2 & 3) * 256 + t;
        int ig = S >> 7, ks = (S >> 6) & 1, ln = S & 63;
        int rc = ig * 16 + (ln & 15);
        int kb = ks * 32 + ((ln >> 4) << 3);
        int n = nt * 128 + rc;
        unsigned short out[8];
#pragma unroll
        for (int j = 0; j < 8; ++j) {
            int k = kc * 64 + kb + j;
            float v = 0.f;
            if (k < 600) {
                if (n < 600) {
                    if (n != 299 && n != 599)
                        v = Y[(size_t)n * 600 + k] + Yconj[(size_t)n * 600 + k];
                } else if (n >= 640 && n < 1536) {
                    int idx = n - 640;
                    int l = idx >> 1, h = idx & 1;
                    if (l < NLINE) v = Atmp[(size_t)(h * NLINE + l) * 600 + k];
                } else if (n >= 1536) {
                    int g = n - 1536;
                    if (g < 138) v = Mapg[(size_t)g * 600 + k];
                }
            }
            out[j] = f2bf(v);
        }
        *(short8*)(BmF + (size_t)(ntkc * 1024 + S) * 8) = *(short8*)out;
    } else {
        // Volt -> padded bf16
        if (!doConv) return;
        int b = (bid - 745) * 4 + w;
        for (int c = lane * 4; c < 600; c += 256) {
            f32x4 x = *(const f32x4*)(Volt + (size_t)b * 600 + c);
            uint2 p;
            p.x = pk2bf(x[0], x[1]);
            p.y = pk2bf(x[2], x[3]);
            *(uint2*)(Vbf + (size_t)b * 640 + c) = p;
        }
        if (lane < 10) {
            uint2 z = make_uint2(0u, 0u);
            *(uint2*)(Vbf + (size_t)b * 640 + 600 + lane * 4) = z;
        }
    }
}

// ---------------- main fused GEMM (2-phase dbuf) + duties + epilogues ----------------
__global__ __launch_bounds__(256, 2) void kkt_main(
    const float* __restrict__ Volt, const float* __restrict__ nolp,
    const float* __restrict__ PG, const float* __restrict__ PL,
    const float* __restrict__ mu_gu, const float* __restrict__ mu_gd,
    const float* __restrict__ mu_vu, const float* __restrict__ mu_vd,
    const float* __restrict__ mu_iu,
    const float* __restrict__ Gmax, const float* __restrict__ Gmin,
    const float* __restrict__ CPg,
    const unsigned short* __restrict__ Vbf, const unsigned short* __restrict__ BmF,
    const float* __restrict__ mapLs, const float* __restrict__ mapgs,
    float* __restrict__ kkt_rows, float* __restrict__ scalar_acc, int useVbf) {

    // XCD-aware swizzle: a rowtile's 14 n-tile blocks share one XCD -> L2 reuse of A rows.
    int idx = blockIdx.x;
    int xcd = idx & 7;
    int q = idx >> 3;
    int nt = q % NTILES;
    int rg = q / NTILES;
    int rt = rg * 8 + xcd;
    int b0 = rt * 128;

    int t = threadIdx.x;
    int lane = t & 63, w = t >> 6, wr = w >> 1, wc = w & 1;

    __shared__ short8 Asm[2][1024];   // A tile dbuf, MFMA-fragment order (32 KB)
    __shared__ short8 Bsm[2][1024];   // B tile dbuf (32 KB)
    __shared__ float  mls[600];
    __shared__ float  redbuf[4];

    bool fastA = (nt < 12) && useVbf;
    const float* Af32 = (nt < 12) ? Volt : nolp;

    for (int j = t; j < 600; j += 256) mls[j] = mapLs[j];

    // per-thread slot geometry for the 4 staging instructions
    int rcA[4], kbA[4];
#pragma unroll
    for (int m = 0; m < 4; ++m) {
        int S = m * 256 + t;
        int ig = S >> 7, ks = (S >> 6) & 1, ln = S & 63;
        rcA[m] = ig * 16 + (ln & 15);
        kbA[m] = ks * 32 + ((ln >> 4) << 3);
    }

    auto issueB = [&](int kc, int pb) {
        const unsigned short* bSrc = BmF + (size_t)(nt * 10 + kc) * 8192;
#pragma unroll
        for (int m = 0; m < 4; ++m) {
            int S = m * 256 + t;
            __builtin_amdgcn_global_load_lds(
                (const __attribute__((address_space(1))) unsigned int*)(bSrc + (size_t)S * 8),
                (__attribute__((address_space(3))) unsigned int*)&Bsm[pb][S], 16, 0, 0);
        }
    };
    auto issueA = [&](int kc, int pb) {
#pragma unroll
        for (int m = 0; m < 4; ++m) {
            int S = m * 256 + t;
            __builtin_amdgcn_global_load_lds(
                (const __attribute__((address_space(1))) unsigned int*)(Vbf + (size_t)(b0 + rcA[m]) * 640 + kc * 64 + kbA[m]),
                (__attribute__((address_space(3))) unsigned int*)&Asm[pb][S], 16, 0, 0);
        }
    };
    auto loadA = [&](int kc, f32x4* xa) {
#pragma unroll
        for (int m = 0; m < 4; ++m) {
            int gk = kc * 64 + kbA[m];
            if (gk < 600) {   // chunks are 8-aligned and 600%8==0, so no partial chunk
                const f32x4* p = (const f32x4*)(Af32 + (size_t)(b0 + rcA[m]) * 600 + gk);
                xa[2 * m] = p[0]; xa[2 * m + 1] = p[1];
            } else {
                f32x4 z = {0.f, 0.f, 0.f, 0.f};
                xa[2 * m] = z; xa[2 * m + 1] = z;
            }
        }
    };
    auto writeA = [&](const f32x4* xa, int pb) {
#pragma unroll
        for (int m = 0; m < 4; ++m) {
            int S = m * 256 + t;
            f32x4 a = xa[2 * m], b = xa[2 * m + 1];
            Asm[pb][S] = __builtin_bit_cast(short8,
                make_uint4(pk2bf(a[0], a[1]), pk2bf(a[2], a[3]),
                           pk2bf(b[0], b[1]), pk2bf(b[2], b[3])));
        }
    };

    // prologue: stage kc=0 into buffer 0
    issueB(0, 0);
    if (fastA) issueA(0, 0);
    else { f32x4 x0[8]; loadA(0, x0); writeA(x0, 0); }
    __syncthreads();

    f32x4 acc[4][4] = {};
    float dscal = 0.f;
    int cur = 0;

    for (int kc = 0; kc < 10; ++kc) {
        int nxt = cur ^ 1;
        bool havN = (kc < 9);
        f32x4 xa[8];
        // prefetch next K-step into the other buffer (overlaps with MFMA below)
        if (havN) {
            issueB(kc + 1, nxt);
            if (fastA) issueA(kc + 1, nxt);
            else       loadA(kc + 1, xa);     // f32 loads issued now, consumed after MFMA
        }

        // ---- MFMA on current buffers ----
        const short8* Ak = Asm[cur];
        const short8* Bk = Bsm[cur];
#pragma unroll
        for (int ks = 0; ks < 2; ++ks) {
            short8 af[4], bfr[4];
#pragma unroll
            for (int ii = 0; ii < 4; ++ii) af[ii] = Ak[((wr * 4 + ii) * 2 + ks) * 64 + lane];
#pragma unroll
            for (int jj = 0; jj < 4; ++jj) bfr[jj] = Bk[((wc * 4 + jj) * 2 + ks) * 64 + lane];
#pragma unroll
            for (int ii = 0; ii < 4; ++ii)
#pragma unroll
                for (int jj = 0; jj < 4; ++jj)
                    acc[ii][jj] = __builtin_amdgcn_mfma_f32_16x16x32_bf16(af[ii], bfr[jj], acc[ii][jj], 0, 0, 0);
        }

        // ---- row duties: rows r_local = nt + 14*i, i = kc*4 + w, at kc = 0..2 ----
        if (kc < 3) {
            int i = kc * 4 + w;
            int rl = nt + 14 * i;
            if (i < 10 && rl < 128) {
                int r = b0 + rl;
                const float* vrow = Volt + (size_t)r * 600;
                float sd = 0.f;
                for (int j = lane * 4; j < 300; j += 256) {
                    f32x4 vr  = *(const f32x4*)(vrow + j);
                    f32x4 vi  = *(const f32x4*)(vrow + 300 + j);
                    f32x4 muu = *(const f32x4*)(mu_vu + (size_t)r * 300 + j);
                    f32x4 mud = *(const f32x4*)(mu_vd + (size_t)r * 300 + j);
#pragma unroll
                    for (int e = 0; e < 4; ++e) {
                        float sq = vr[e] * vr[e], si = vi[e] * vi[e];
                        float vu = sq + si - 1.1236f;
                        float vd = 0.8836f - sq + si;
                        sd += fmaxf(vu, 0.f) + fmaxf(vd, 0.f)
                            + fabsf(muu[e] * vu) + fabsf(mud[e] * vd)
                            + fmaxf(-muu[e], 0.f) + fmaxf(-mud[e], 0.f);
                    }
                }
                float s2 = 0.f;
                for (int j = lane * 4; j < 600; j += 256) {
                    f32x4 pl = *(const f32x4*)(PL + (size_t)r * 600 + j);
#pragma unroll
                    for (int e = 0; e < 4; ++e) s2 += pl[e] * mls[j + e];
                }
                sd += 32768.0f * s2;
                for (int m = 32; m >= 1; m >>= 1) sd += __shfl_xor(sd, m);
                if (lane == 0) {
                    atomicAdd(kkt_rows + r, sd);
                    dscal += fabsf(vrow[300]);
                }
            }
        }

        // slow-A path: convert the early-issued f32 loads, write into next buffer
        if (havN && !fastA) writeA(xa, nxt);

        __syncthreads();   // drains vm+lgkm: next buffers ready, current safe to overwrite
        cur = nxt;
    }

    if (lane == 0 && dscal != 0.f) atomicAdd(scalar_acc, dscal);

    // ---- section epilogues ----
    // C/D layout (m89): col = lane&15, row = (lane>>4)*4 + reg
    if (nt < 5) {
        // quad: global scalar += sum u*v  (v read fp32 for accuracy)
        float qa = 0.f;
#pragma unroll
        for (int ii = 0; ii < 4; ++ii)
#pragma unroll
            for (int jj = 0; jj < 4; ++jj)
#pragma unroll
                for (int r2 = 0; r2 < 4; ++r2) {
                    int row = wr * 64 + ii * 16 + ((lane >> 4) << 2) + r2;
                    int col = nt * 128 + wc * 64 + jj * 16 + (lane & 15);
                    if (col < 600) {
                        float v = Volt[(size_t)(b0 + row) * 600 + col];
                        qa += acc[ii][jj][r2] * v;
                    }
                }
        for (int m = 32; m >= 1; m >>= 1) qa += __shfl_xor(qa, m);
        if (lane == 0) redbuf[w] = qa;
        __syncthreads();
        if (t == 0) atomicAdd(scalar_acc, redbuf[0] + redbuf[1] + redbuf[2] + redbuf[3]);
    } else if (nt < 12) {
        // Ibr: i_up = re^2 + im^2 - 1 on interleaved column pairs
        float racc[16];
#pragma unroll
        for (int s = 0; s < 16; ++s) racc[s] = 0.f;
#pragma unroll
        for (int ii = 0; ii < 4; ++ii)
#pragma unroll
            for (int jj = 0; jj < 4; ++jj)
#pragma unroll
                for (int r2 = 0; r2 < 4; ++r2) {
                    float u = acc[ii][jj][r2];
                    float up = __shfl_xor(u, 1);
                    int col = nt * 128 + wc * 64 + jj * 16 + (lane & 15);
                    int l = (col - 640) >> 1;
                    float contrib = 0.f;
                    if (l < NLINE && !(lane & 1)) {
                        int row = wr * 64 + ii * 16 + ((lane >> 4) << 2) + r2;
                        float iu = u * u + up * up - 1.0f;
                        float mu = mu_iu[(size_t)(b0 + row) * NLINE + l];
                        contrib = fmaxf(iu, 0.f) + fabsf(mu * iu) + fmaxf(-mu, 0.f);
                    }
                    racc[ii * 4 + r2] += contrib;
                }
#pragma unroll
        for (int s = 0; s < 16; ++s) {
            float v = racc[s];
            v += __shfl_xor(v, 1); v += __shfl_xor(v, 2);
            v += __shfl_xor(v, 4); v += __shfl_xor(v, 8);
            if ((lane & 15) == 0) {
                int row = wr * 64 + (s >> 2) * 16 + ((lane >> 4) << 2) + (s & 3);
                atomicAdd(kkt_rows + b0 + row, v);
            }
        }
    } else {
        // stat + gen-limit terms + P_Gens part of mism
        float racc[16];
#pragma unroll
        for (int s = 0; s < 16; ++s) racc[s] = 0.f;
#pragma unroll
        for (int ii = 0; ii < 4; ++ii)
#pragma unroll
            for (int jj = 0; jj < 4; ++jj)
#pragma unroll
                for (int r2 = 0; r2 < 4; ++r2) {
                    int col = nt * 128 + wc * 64 + jj * 16 + (lane & 15);
                    int g = col - 1536;
                    float contrib = 0.f;
                    if (g < 138) {
                        int row = wr * 64 + ii * 16 + ((lane >> 4) << 2) + r2;
                        size_t ix = (size_t)(b0 + row) * 138 + g;
                        float u = acc[ii][jj][r2];
                        float gu = mu_gu[ix], gd = mu_gd[ix], pg = PG[ix];
                        float gmx = Gmax[g], gmn = Gmin[g];
                        float cst = (g < 69) ? CPg[g] : 0.f;
                        float t1 = pg - gmx, t2 = gmn - pg;
                        float st = u + gu - gd - cst;
                        contrib = fabsf(st) + fmaxf(t1, 0.f) + fmaxf(t2, 0.f)
                                + (fabsf(gu * t1) + fabsf(gd * t2)) * (1.0f / 69.0f)
                                + fmaxf(-gu, 0.f) + fmaxf(-gd, 0.f)
                                - 32768.0f * pg * mapgs[g];
                    }
                    racc[ii * 4 + r2] += contrib;
                }
#pragma unroll
        for (int s = 0; s < 16; ++s) {
            float v = racc[s];
            v += __shfl_xor(v, 1); v += __shfl_xor(v, 2);
            v += __shfl_xor(v, 4); v += __shfl_xor(v, 8);
            if ((lane & 15) == 0) {
                int row = wr * 64 + (s >> 2) * 16 + ((lane >> 4) << 2) + (s & 3);
                atomicAdd(kkt_rows + b0 + row, v);
            }
        }
    }
}

// ---------------- finalize ----------------
__global__ void finalize_k(const float* __restrict__ kkt_rows, const float* __restrict__ scalar_acc,
                           float* __restrict__ out) {
    int i = blockIdx.x * 256 + threadIdx.x;
    out[i] = kkt_rows[i] + scalar_acc[0];
}

extern "C" void kernel_launch(void* const* d_in, const int* in_sizes, int n_in,
                              void* d_out, int out_size, void* d_ws, size_t ws_size,
                              hipStream_t stream) {
    const float* Volt  = (const float*)d_in[0];
    const float* PG    = (const float*)d_in[1];
    const float* PL    = (const float*)d_in[2];
    const float* nolp  = (const float*)d_in[3];
    const float* mu_gu = (const float*)d_in[4];
    const float* mu_gd = (const float*)d_in[5];
    const float* mu_vu = (const float*)d_in[6];
    const float* mu_vd = (const float*)d_in[7];
    const float* mu_iu = (const float*)d_in[8];
    const float* Y     = (const float*)d_in[9];
    const float* Yconj = (const float*)d_in[10];
    const float* Ybr   = (const float*)d_in[11];
    const float* IM    = (const float*)d_in[12];
    const float* Mapg  = (const float*)d_in[13];
    const float* MapL  = (const float*)d_in[14];
    const float* Gmax  = (const float*)d_in[15];
    const float* Gmin  = (const float*)d_in[16];
    const float* CPg   = (const float*)d_in[17];

    char* ws = (char*)d_ws;
    float* scalar_acc       = (float*)(ws + WS_SCALAR);
    float* kkt_rows         = (float*)(ws + WS_KROWS);
    float* mapLs            = (float*)(ws + WS_MAPL);
    float* mapgs            = (float*)(ws + WS_MAPG);
    float* Atmp             = (float*)(ws + WS_ATMP);
    unsigned short* BmF     = (unsigned short*)(ws + WS_BMF);
    unsigned short* Vbf     = (unsigned short*)(ws + WS_VBF);

    int useVbf = (ws_size >= (size_t)WS_NEED_FAST) ? 1 : 0;

    hipMemsetAsync(d_ws, 0, WS_ZERO_BYTES, stream);
    prep_A<<<520, 256, 0, stream>>>(Ybr, IM, Atmp);
    prep_misc<<<185 + 560 + 8192, 256, 0, stream>>>(MapL, Mapg, mapLs, mapgs,
                                                    Y, Yconj, Atmp, BmF, Volt, Vbf, useVbf);
    kkt_main<<<RTILES * NTILES, 256, 0, stream>>>(Volt, nolp, PG, PL, mu_gu, mu_gd,
                                                  mu_vu, mu_vd, mu_iu, Gmax, Gmin, CPg,
                                                  Vbf, BmF, mapLs, mapgs,
                                                  kkt_rows, scalar_acc, useVbf);
    finalize_k<<<BATCH / 256, 256, 0, stream>>>(kkt_rows, scalar_acc, (float*)d_out);
}

// Round 3
// 747.152 us; speedup vs baseline: 1.4519x; 1.0930x over previous
//
#include <hip/hip_runtime.h>

// ---------------- problem constants ----------------
#define BATCH   32768
#define NLINE   411
#define NTILES  14            // 5 quad + 7 Ibr + 2 stat n-tiles of 128
#define RTILES  256           // 32768 / 128

typedef __attribute__((ext_vector_type(8))) short  short8;
typedef __attribute__((ext_vector_type(4))) float  f32x4;

// ---------------- workspace layout (bytes) ----------------
#define WS_SCALAR   0
#define WS_KROWS    64                       // 32768 f32
#define WS_MAPL     131136                   // 600 f32
#define WS_MAPG     133536                   // 138 f32 (pad to 134144)
#define WS_ATMP     134144                   // 822*600 f32 = 1972800
#define WS_BMF      2106944                  // 14*10*1024*16 = 2293760
#define WS_VBF      4400704                  // 256*10*1024*16 = 41943040 (fragment-packed)
#define WS_NEED_FAST (4400704 + 41943040)    // 46343744
#define WS_ZERO_BYTES 2106944                // scalar..Atmp

__device__ __forceinline__ unsigned short f2bf(float f) {
    unsigned int u = __float_as_uint(f);
    unsigned int r = (u + 0x7FFFu + ((u >> 16) & 1u)) >> 16;
    return (unsigned short)r;
}

#if defined(__has_builtin)
#  if __has_builtin(__builtin_amdgcn_cvt_pk_bf16_f32)
#    define HAVE_PK_BF16 1
#  endif
#endif

__device__ __forceinline__ unsigned int pk2bf(float a, float b) {
#ifdef HAVE_PK_BF16
    typedef __bf16 bf16x2 __attribute__((ext_vector_type(2)));
    bf16x2 r = __builtin_amdgcn_cvt_pk_bf16_f32(a, b);
    return __builtin_bit_cast(unsigned int, r);
#else
    return (unsigned int)f2bf(a) | ((unsigned int)f2bf(b) << 16);
#endif
}

// ---------------- prep: A = Ybr @ IM  (822x600), split-K fp32 with atomics ----------------
__global__ __launch_bounds__(256) void prep_A(const float* __restrict__ Ybr,
                                              const float* __restrict__ IM,
                                              float* __restrict__ Atmp) {
    int bid = blockIdx.x;
    int ks = bid & 3;
    int t2 = bid >> 2;
    int bc = t2 % 10, br = t2 / 10;          // 13 x 10 tiles of 64x64
    int r0 = br * 64, c0 = bc * 64;
    int kb = ks * 206;
    int ke = (kb + 206 < 822) ? kb + 206 : 822;

    __shared__ float Yt[64][33];
    __shared__ float Xt[32][65];
    int t = threadIdx.x;
    int tx = t & 15, ty = t >> 4;
    float c[4][4] = {};

    for (int kk = kb; kk < ke; kk += 32) {
        __syncthreads();
        for (int e = t; e < 2048; e += 256) {
            int yr = e >> 5, yk = e & 31;
            int gr = r0 + yr, gk = kk + yk;
            Yt[yr][yk] = (gr < 822 && gk < ke) ? Ybr[(size_t)gr * 822 + gk] : 0.f;
        }
        for (int e = t; e < 2048; e += 256) {
            int xk = e >> 6, xc = e & 63;
            int gk = kk + xk, gc = c0 + xc;
            Xt[xk][xc] = (gk < ke && gc < 600) ? IM[(size_t)gk * 600 + gc] : 0.f;
        }
        __syncthreads();
        for (int k2 = 0; k2 < 32; ++k2) {
            float a[4], b[4];
#pragma unroll
            for (int ii = 0; ii < 4; ++ii) a[ii] = Yt[ty * 4 + ii][k2];
#pragma unroll
            for (int jj = 0; jj < 4; ++jj) b[jj] = Xt[k2][tx * 4 + jj];
#pragma unroll
            for (int ii = 0; ii < 4; ++ii)
#pragma unroll
                for (int jj = 0; jj < 4; ++jj) c[ii][jj] += a[ii] * b[jj];
        }
    }
#pragma unroll
    for (int ii = 0; ii < 4; ++ii)
#pragma unroll
        for (int jj = 0; jj < 4; ++jj) {
            int gr = r0 + ty * 4 + ii, gc = c0 + tx * 4 + jj;
            if (gr < 822 && gc < 600) atomicAdd(Atmp + (size_t)gr * 600 + gc, c[ii][jj]);
        }
}

// ---------------- prep_misc: colsums (185) + packF (560) + Volt->VbfF frag-pack (2560) ----------------
// frag slot S -> (rc,kb): ig=S>>7, ks=(S>>6)&1, ln=S&63, rc = ig*16+(ln&15), kb = ks*32+((ln>>4)<<3)
__global__ __launch_bounds__(256) void prep_misc(
    const float* __restrict__ MapL, const float* __restrict__ Mapg,
    float* __restrict__ mapL_s, float* __restrict__ mapg_s,
    const float* __restrict__ Y, const float* __restrict__ Yconj,
    const float* __restrict__ Atmp, unsigned short* __restrict__ BmF,
    const float* __restrict__ Volt, unsigned short* __restrict__ VbfF, int doConv) {
    int bid = blockIdx.x;
    int t = threadIdx.x;
    int w = t >> 6, lane = t & 63;

    if (bid < 185) {
        // masked column sums for mism
        int row = bid * 4 + w;
        const float* src;
        float* dst;
        if (row < 600)      { src = MapL + (size_t)row * 600; dst = mapL_s + row; }
        else if (row < 738) { src = Mapg + (size_t)(row - 600) * 600; dst = mapg_s + (row - 600); }
        else return;
        float s = 0.f;
        for (int j = lane; j < 600; j += 64)
            if (j != 299 && j != 599) s += src[j];
        for (int m = 32; m >= 1; m >>= 1) s += __shfl_xor(s, m);
        if (lane == 0) *dst = s;
    } else if (bid < 745) {
        // pack combined B into MFMA-fragment order per (nt,kc)
        int b2 = bid - 185;
        int ntkc = b2 >> 2;
        int nt = ntkc / 10, kc = ntkc % 10;
        int S = (b2 & 3) * 256 + t;
        int ig = S >> 7, ks = (S >> 6) & 1, ln = S & 63;
        int rc = ig * 16 + (ln & 15);
        int kb = ks * 32 + ((ln >> 4) << 3);
        int n = nt * 128 + rc;
        unsigned short out[8];
#pragma unroll
        for (int j = 0; j < 8; ++j) {
            int k = kc * 64 + kb + j;
            float v = 0.f;
            if (k < 600) {
                if (n < 600) {
                    if (n != 299 && n != 599)
                        v = Y[(size_t)n * 600 + k] + Yconj[(size_t)n * 600 + k];
                } else if (n >= 640 && n < 1536) {
                    int idx = n - 640;
                    int l = idx >> 1, h = idx & 1;
                    if (l < NLINE) v = Atmp[(size_t)(h * NLINE + l) * 600 + k];
                } else if (n >= 1536) {
                    int g = n - 1536;
                    if (g < 138) v = Mapg[(size_t)g * 600 + k];
                }
            }
            out[j] = f2bf(v);
        }
        *(short8*)(BmF + (size_t)(ntkc * 1024 + S) * 8) = *(short8*)out;
    } else {
        // Volt -> fragment-packed bf16 per (rowtile, kc): coalesced 16KB blocks for kkt_main
        if (!doConv) return;
        int b2 = bid - 745;            // 0..2559
        int rt = b2 / 10, kc = b2 % 10;
        int b0 = rt * 128;
        unsigned short* dst = VbfF + (size_t)(rt * 10 + kc) * 8192;
#pragma unroll
        for (int m = 0; m < 4; ++m) {
            int S = m * 256 + t;
            int ig = S >> 7, ks = (S >> 6) & 1, ln = S & 63;
            int rc = ig * 16 + (ln & 15);
            int kb = ks * 32 + ((ln >> 4) << 3);
            int k = kc * 64 + kb;
            short8 outv = (short8)0;
            if (k < 600) {   // chunks 8-aligned, 600%8==0: all-in or all-out
                const f32x4* p = (const f32x4*)(Volt + (size_t)(b0 + rc) * 600 + k);
                f32x4 a = p[0], b = p[1];
                outv = __builtin_bit_cast(short8,
                    make_uint4(pk2bf(a[0], a[1]), pk2bf(a[2], a[3]),
                               pk2bf(b[0], b[1]), pk2bf(b[2], b[3])));
            }
            *(short8*)(dst + (size_t)S * 8) = outv;
        }
    }
}

// ---------------- main fused GEMM (single-buffer, occupancy-first) + duties + epilogues ----------------
__global__ __launch_bounds__(256, 4) void kkt_main(
    const float* __restrict__ Volt, const float* __restrict__ nolp,
    const float* __restrict__ PG, const float* __restrict__ PL,
    const float* __restrict__ mu_gu, const float* __restrict__ mu_gd,
    const float* __restrict__ mu_vu, const float* __restrict__ mu_vd,
    const float* __restrict__ mu_iu,
    const float* __restrict__ Gmax, const float* __restrict__ Gmin,
    const float* __restrict__ CPg,
    const unsigned short* __restrict__ VbfF, const unsigned short* __restrict__ BmF,
    const float* __restrict__ mapLs, const float* __restrict__ mapgs,
    float* __restrict__ kkt_rows, float* __restrict__ scalar_acc, int useVbf) {

    // XCD-aware swizzle: a rowtile's 14 n-tile blocks share one XCD -> L2 reuse of VbfF[rt].
    int idx = blockIdx.x;
    int xcd = idx & 7;
    int q = idx >> 3;
    int nt = q % NTILES;
    int rg = q / NTILES;
    int rt = rg * 8 + xcd;
    int b0 = rt * 128;

    int t = threadIdx.x;
    int lane = t & 63, w = t >> 6, wr = w >> 1, wc = w & 1;

    __shared__ short8 Asm[1024];   // A tile, MFMA-fragment order (16 KB)
    __shared__ short8 Bsm[1024];   // B tile (16 KB)
    __shared__ float  mls[600];
    __shared__ float  redbuf[4];

    bool fastA = (nt < 12) && useVbf;
    const float* Af32 = (nt < 12) ? Volt : nolp;

    for (int j = t; j < 600; j += 256) mls[j] = mapLs[j];
    __syncthreads();   // mls visible before duty at kc=0

    // per-thread slot geometry (slow-A path)
    int rcA[4], kbA[4];
#pragma unroll
    for (int m = 0; m < 4; ++m) {
        int S = m * 256 + t;
        int ig = S >> 7, ks = (S >> 6) & 1, ln = S & 63;
        rcA[m] = ig * 16 + (ln & 15);
        kbA[m] = ks * 32 + ((ln >> 4) << 3);
    }

    f32x4 acc[4][4] = {};
    float dscal = 0.f;

    for (int kc = 0; kc < 10; ++kc) {
        if (kc) __syncthreads();          // previous compute done reading LDS

        // ---- stage kc (B always via lds-DMA; A via lds-DMA when frag-packed) ----
        {
            const unsigned short* bSrc = BmF + (size_t)(nt * 10 + kc) * 8192;
#pragma unroll
            for (int m = 0; m < 4; ++m) {
                int S = m * 256 + t;
                __builtin_amdgcn_global_load_lds(
                    (const __attribute__((address_space(1))) unsigned int*)(bSrc + (size_t)S * 8),
                    (__attribute__((address_space(3))) unsigned int*)&Bsm[S], 16, 0, 0);
            }
        }
        if (fastA) {
            const unsigned short* aSrc = VbfF + (size_t)(rt * 10 + kc) * 8192;
#pragma unroll
            for (int m = 0; m < 4; ++m) {
                int S = m * 256 + t;
                __builtin_amdgcn_global_load_lds(
                    (const __attribute__((address_space(1))) unsigned int*)(aSrc + (size_t)S * 8),
                    (__attribute__((address_space(3))) unsigned int*)&Asm[S], 16, 0, 0);
            }
        } else {
            // f32 gather -> convert -> LDS write (short liveness: no span across MFMA)
            f32x4 xa[8];
#pragma unroll
            for (int m = 0; m < 4; ++m) {
                int gk = kc * 64 + kbA[m];
                if (gk < 600) {
                    const f32x4* p = (const f32x4*)(Af32 + (size_t)(b0 + rcA[m]) * 600 + gk);
                    xa[2 * m] = p[0]; xa[2 * m + 1] = p[1];
                } else {
                    f32x4 z = {0.f, 0.f, 0.f, 0.f};
                    xa[2 * m] = z; xa[2 * m + 1] = z;
                }
            }
#pragma unroll
            for (int m = 0; m < 4; ++m) {
                int S = m * 256 + t;
                f32x4 a = xa[2 * m], b = xa[2 * m + 1];
                Asm[S] = __builtin_bit_cast(short8,
                    make_uint4(pk2bf(a[0], a[1]), pk2bf(a[2], a[3]),
                               pk2bf(b[0], b[1]), pk2bf(b[2], b[3])));
            }
        }

        // ---- row duties overlap the staging flight: rows rl = nt + 14*i, i = kc*4 + w ----
        if (kc < 3) {
            int i = kc * 4 + w;
            int rl = nt + 14 * i;
            if (i < 10 && rl < 128) {
                int r = b0 + rl;
                const float* vrow = Volt + (size_t)r * 600;
                float sd = 0.f;
                for (int j = lane * 4; j < 300; j += 256) {
                    f32x4 vr  = *(const f32x4*)(vrow + j);
                    f32x4 vi  = *(const f32x4*)(vrow + 300 + j);
                    f32x4 muu = *(const f32x4*)(mu_vu + (size_t)r * 300 + j);
                    f32x4 mud = *(const f32x4*)(mu_vd + (size_t)r * 300 + j);
#pragma unroll
                    for (int e = 0; e < 4; ++e) {
                        float sq = vr[e] * vr[e], si = vi[e] * vi[e];
                        float vu = sq + si - 1.1236f;
                        float vd = 0.8836f - sq + si;
                        sd += fmaxf(vu, 0.f) + fmaxf(vd, 0.f)
                            + fabsf(muu[e] * vu) + fabsf(mud[e] * vd)
                            + fmaxf(-muu[e], 0.f) + fmaxf(-mud[e], 0.f);
                    }
                }
                float s2 = 0.f;
                for (int j = lane * 4; j < 600; j += 256) {
                    f32x4 pl = *(const f32x4*)(PL + (size_t)r * 600 + j);
#pragma unroll
                    for (int e = 0; e < 4; ++e) s2 += pl[e] * mls[j + e];
                }
                sd += 32768.0f * s2;
                for (int m = 32; m >= 1; m >>= 1) sd += __shfl_xor(sd, m);
                if (lane == 0) {
                    atomicAdd(kkt_rows + r, sd);
                    dscal += fabsf(vrow[300]);
                }
            }
        }

        __syncthreads();   // drain: tiles ready

        // ---- MFMA ----
#pragma unroll
        for (int ks = 0; ks < 2; ++ks) {
            short8 af[4], bfr[4];
#pragma unroll
            for (int ii = 0; ii < 4; ++ii) af[ii] = Asm[((wr * 4 + ii) * 2 + ks) * 64 + lane];
#pragma unroll
            for (int jj = 0; jj < 4; ++jj) bfr[jj] = Bsm[((wc * 4 + jj) * 2 + ks) * 64 + lane];
#pragma unroll
            for (int ii = 0; ii < 4; ++ii)
#pragma unroll
                for (int jj = 0; jj < 4; ++jj)
                    acc[ii][jj] = __builtin_amdgcn_mfma_f32_16x16x32_bf16(af[ii], bfr[jj], acc[ii][jj], 0, 0, 0);
        }
    }

    if (lane == 0 && dscal != 0.f) atomicAdd(scalar_acc, dscal);

    // ---- section epilogues ----
    // C/D layout (m89): col = lane&15, row = (lane>>4)*4 + reg
    if (nt < 5) {
        // quad: global scalar += sum u*v  (v read fp32 for accuracy)
        float qa = 0.f;
#pragma unroll
        for (int ii = 0; ii < 4; ++ii)
#pragma unroll
            for (int jj = 0; jj < 4; ++jj)
#pragma unroll
                for (int r2 = 0; r2 < 4; ++r2) {
                    int row = wr * 64 + ii * 16 + ((lane >> 4) << 2) + r2;
                    int col = nt * 128 + wc * 64 + jj * 16 + (lane & 15);
                    if (col < 600) {
                        float v = Volt[(size_t)(b0 + row) * 600 + col];
                        qa += acc[ii][jj][r2] * v;
                    }
                }
        for (int m = 32; m >= 1; m >>= 1) qa += __shfl_xor(qa, m);
        if (lane == 0) redbuf[w] = qa;
        __syncthreads();
        if (t == 0) atomicAdd(scalar_acc, redbuf[0] + redbuf[1] + redbuf[2] + redbuf[3]);
    } else if (nt < 12) {
        // Ibr: i_up = re^2 + im^2 - 1 on interleaved column pairs
        float racc[16];
#pragma unroll
        for (int s = 0; s < 16; ++s) racc[s] = 0.f;
#pragma unroll
        for (int ii = 0; ii < 4; ++ii)
#pragma unroll
            for (int jj = 0; jj < 4; ++jj)
#pragma unroll
                for (int r2 = 0; r2 < 4; ++r2) {
                    float u = acc[ii][jj][r2];
                    float up = __shfl_xor(u, 1);
                    int col = nt * 128 + wc * 64 + jj * 16 + (lane & 15);
                    int l = (col - 640) >> 1;
                    float contrib = 0.f;
                    if (l < NLINE && !(lane & 1)) {
                        int row = wr * 64 + ii * 16 + ((lane >> 4) << 2) + r2;
                        float iu = u * u + up * up - 1.0f;
                        float mu = mu_iu[(size_t)(b0 + row) * NLINE + l];
                        contrib = fmaxf(iu, 0.f) + fabsf(mu * iu) + fmaxf(-mu, 0.f);
                    }
                    racc[ii * 4 + r2] += contrib;
                }
#pragma unroll
        for (int s = 0; s < 16; ++s) {
            float v = racc[s];
            v += __shfl_xor(v, 1); v += __shfl_xor(v, 2);
            v += __shfl_xor(v, 4); v += __shfl_xor(v, 8);
            if ((lane & 15) == 0) {
                int row = wr * 64 + (s >> 2) * 16 + ((lane >> 4) << 2) + (s & 3);
                atomicAdd(kkt_rows + b0 + row, v);
            }
        }
    } else {
        // stat + gen-limit terms + P_Gens part of mism
        float racc[16];
#pragma unroll
        for (int s = 0; s < 16; ++s) racc[s] = 0.f;
#pragma unroll
        for (int ii = 0; ii < 4; ++ii)
#pragma unroll
            for (int jj = 0; jj < 4; ++jj)
#pragma unroll
                for (int r2 = 0; r2 < 4; ++r2) {
                    int col = nt * 128 + wc * 64 + jj * 16 + (lane & 15);
                    int g = col - 1536;
                    float contrib = 0.f;
                    if (g < 138) {
                        int row = wr * 64 + ii * 16 + ((lane >> 4) << 2) + r2;
                        size_t ix = (size_t)(b0 + row) * 138 + g;
                        float u = acc[ii][jj][r2];
                        float gu = mu_gu[ix], gd = mu_gd[ix], pg = PG[ix];
                        float gmx = Gmax[g], gmn = Gmin[g];
                        float cst = (g < 69) ? CPg[g] : 0.f;
                        float t1 = pg - gmx, t2 = gmn - pg;
                        float st = u + gu - gd - cst;
                        contrib = fabsf(st) + fmaxf(t1, 0.f) + fmaxf(t2, 0.f)
                                + (fabsf(gu * t1) + fabsf(gd * t2)) * (1.0f / 69.0f)
                                + fmaxf(-gu, 0.f) + fmaxf(-gd, 0.f)
                                - 32768.0f * pg * mapgs[g];
                    }
                    racc[ii * 4 + r2] += contrib;
                }
#pragma unroll
        for (int s = 0; s < 16; ++s) {
            float v = racc[s];
            v += __shfl_xor(v, 1); v += __shfl_xor(v, 2);
            v += __shfl_xor(v, 4); v += __shfl_xor(v, 8);
            if ((lane & 15) == 0) {
                int row = wr * 64 + (s >> 2) * 16 + ((lane >> 4) << 2) + (s & 3);
                atomicAdd(kkt_rows + b0 + row, v);
            }
        }
    }
}

// ---------------- finalize ----------------
__global__ void finalize_k(const float* __restrict__ kkt_rows, const float* __restrict__ scalar_acc,
                           float* __restrict__ out) {
    int i = blockIdx.x * 256 + threadIdx.x;
    out[i] = kkt_rows[i] + scalar_acc[0];
}

extern "C" void kernel_launch(void* const* d_in, const int* in_sizes, int n_in,
                              void* d_out, int out_size, void* d_ws, size_t ws_size,
                              hipStream_t stream) {
    const float* Volt  = (const float*)d_in[0];
    const float* PG    = (const float*)d_in[1];
    const float* PL    = (const float*)d_in[2];
    const float* nolp  = (const float*)d_in[3];
    const float* mu_gu = (const float*)d_in[4];
    const float* mu_gd = (const float*)d_in[5];
    const float* mu_vu = (const float*)d_in[6];
    const float* mu_vd = (const float*)d_in[7];
    const float* mu_iu = (const float*)d_in[8];
    const float* Y     = (const float*)d_in[9];
    const float* Yconj = (const float*)d_in[10];
    const float* Ybr   = (const float*)d_in[11];
    const float* IM    = (const float*)d_in[12];
    const float* Mapg  = (const float*)d_in[13];
    const float* MapL  = (const float*)d_in[14];
    const float* Gmax  = (const float*)d_in[15];
    const float* Gmin  = (const float*)d_in[16];
    const float* CPg   = (const float*)d_in[17];

    char* ws = (char*)d_ws;
    float* scalar_acc       = (float*)(ws + WS_SCALAR);
    float* kkt_rows         = (float*)(ws + WS_KROWS);
    float* mapLs            = (float*)(ws + WS_MAPL);
    float* mapgs            = (float*)(ws + WS_MAPG);
    float* Atmp             = (float*)(ws + WS_ATMP);
    unsigned short* BmF     = (unsigned short*)(ws + WS_BMF);
    unsigned short* VbfF    = (unsigned short*)(ws + WS_VBF);

    int useVbf = (ws_size >= (size_t)WS_NEED_FAST) ? 1 : 0;

    hipMemsetAsync(d_ws, 0, WS_ZERO_BYTES, stream);
    prep_A<<<520, 256, 0, stream>>>(Ybr, IM, Atmp);
    prep_misc<<<185 + 560 + 2560, 256, 0, stream>>>(MapL, Mapg, mapLs, mapgs,
                                                    Y, Yconj, Atmp, BmF, Volt, VbfF, useVbf);
    kkt_main<<<RTILES * NTILES, 256, 0, stream>>>(Volt, nolp, PG, PL, mu_gu, mu_gd,
                                                  mu_vu, mu_vd, mu_iu, Gmax, Gmin, CPg,
                                                  VbfF, BmF, mapLs, mapgs,
                                                  kkt_rows, scalar_acc, useVbf);
    finalize_k<<<BATCH / 256, 256, 0, stream>>>(kkt_rows, scalar_acc, (float*)d_out);
}